// Round 4
// baseline (316.465 us; speedup 1.0000x reference)
//
#include <hip/hip_runtime.h>
#include <hip/hip_fp16.h>
#include <math.h>

#define IN_DIM 256
#define L1_DIM 16

// ---------------- proj kernel ----------------
// Block = 512 threads = 8 waves over a 64-node tile. Wave w owns j-pair
// {2w, 2w+1} for BOTH tables (acc[4]): 1 LDS read feeds 4 FMAs, 6.1
// waves/SIMD. z staged in LDS (stride 66 -> ds_read_b64 2-way = free),
// 2-deep register prefetch so loads are covered by ~2 chunks of FMA.
// Trailing blocks convert w1_l2/w2_l2 to fp16 for the edge kernel.
#define NPB 64
#define KC 64
#define NCHUNK (IN_DIM / KC)    // 4
#define ZSTRIDE 66              // even (float2-aligned), (2i+2k)%32 -> 2-way
#define PBLOCK 512
#define F4PT 2                  // (64*64/4) float4 slots / 512 threads

__global__ __launch_bounds__(PBLOCK) void proj_kernel(
    const float* __restrict__ z,
    const float* __restrict__ w1,     // [256][16]
    const float* __restrict__ w2,
    const float* __restrict__ w1_l2,  // [1000][16]
    const float* __restrict__ w2_l2,
    __half* __restrict__ h1,
    __half* __restrict__ h2,
    __half* __restrict__ w1h,
    __half* __restrict__ w2h,
    int n_nodes, int nblocks_proj) {
  // trailing blocks: convert level-2 weight tables to fp16
  if ((int)blockIdx.x >= nblocks_proj) {
    int t0 = ((int)blockIdx.x - nblocks_proj) * PBLOCK + (int)threadIdx.x;
    const int total = 1000 * L1_DIM;  // 16000
    for (int i = t0; i < total; i += 8 * PBLOCK) {
      w1h[i] = __float2half(w1_l2[i]);
      w2h[i] = __float2half(w2_l2[i]);
    }
    return;
  }

  __shared__ float zs[2][NPB * ZSTRIDE];   // 33.8 KB

  const int tid  = threadIdx.x;
  const int lane = tid & 63;
  const int wv   = __builtin_amdgcn_readfirstlane(tid >> 6);  // 0..7
  const int j0   = wv * 2;                                    // j-pair base
  const int node0 = (int)blockIdx.x * NPB;

  float acc[4];  // {w1:j0, w1:j0+1, w2:j0, w2:j0+1}
#pragma unroll
  for (int j = 0; j < 4; ++j) acc[j] = 0.f;

  float4 bufA[F4PT], bufB[F4PT];

  auto issue = [&](int c, float4* bf) {
#pragma unroll
    for (int r = 0; r < F4PT; ++r) {
      int slot = r * PBLOCK + tid;   // 0..1023
      int nd = slot >> 4;            // node within tile (16 f4/row-chunk)
      int c4 = slot & 15;
      int ng = node0 + nd;
      if (ng >= n_nodes) ng = n_nodes - 1;
      bf[r] = *reinterpret_cast<const float4*>(
          z + (size_t)ng * IN_DIM + c * KC + c4 * 4);
    }
  };
  auto lwrite = [&](int b, const float4* bf) {
#pragma unroll
    for (int r = 0; r < F4PT; ++r) {
      int slot = r * PBLOCK + tid;
      int nd = slot >> 4;
      int c4 = slot & 15;
      float* p = &zs[b][nd * ZSTRIDE + c4 * 4];
      float2 lo, hi;
      lo.x = bf[r].x; lo.y = bf[r].y; hi.x = bf[r].z; hi.y = bf[r].w;
      *reinterpret_cast<float2*>(p)     = lo;   // 8B-aligned (stride even)
      *reinterpret_cast<float2*>(p + 2) = hi;
    }
  };

  issue(0, bufA);
  issue(1, bufB);
  lwrite(0, bufA);
  __syncthreads();

#pragma unroll
  for (int c = 0; c < NCHUNK; ++c) {
    if (c + 2 < NCHUNK) issue(c + 2, (c & 1) ? bufB : bufA);

    const float* zrow = &zs[c & 1][lane * ZSTRIDE];
#pragma unroll
    for (int k2 = 0; k2 < KC / 2; ++k2) {
      float2 zk = *reinterpret_cast<const float2*>(zrow + 2 * k2); // b64, free
      int kg = c * KC + 2 * k2;
      const float* w1r = w1 + (size_t)kg * L1_DIM + j0;  // wave-uniform
      const float* w2r = w2 + (size_t)kg * L1_DIM + j0;
      acc[0] = fmaf(zk.x, w1r[0], acc[0]);
      acc[1] = fmaf(zk.x, w1r[1], acc[1]);
      acc[2] = fmaf(zk.x, w2r[0], acc[2]);
      acc[3] = fmaf(zk.x, w2r[1], acc[3]);
      acc[0] = fmaf(zk.y, w1r[L1_DIM + 0], acc[0]);
      acc[1] = fmaf(zk.y, w1r[L1_DIM + 1], acc[1]);
      acc[2] = fmaf(zk.y, w2r[L1_DIM + 0], acc[2]);
      acc[3] = fmaf(zk.y, w2r[L1_DIM + 1], acc[3]);
    }

    if (c + 1 < NCHUNK) {
      lwrite((c + 1) & 1, (c & 1) ? bufA : bufB);
      __syncthreads();
    }
  }

  int node = node0 + lane;
  if (node < n_nodes) {
    __half2 o1 = __floats2half2_rn(fmaxf(acc[0], 0.f), fmaxf(acc[1], 0.f));
    __half2 o2 = __floats2half2_rn(fmaxf(acc[2], 0.f), fmaxf(acc[3], 0.f));
    *reinterpret_cast<__half2*>(h1 + (size_t)node * L1_DIM + j0) = o1;
    *reinterpret_cast<__half2*>(h2 + (size_t)node * L1_DIM + j0) = o2;
  }
}

// ---------------- edge kernel ----------------
// fp16 h tables (1.6 MB each) + fp16 w tables (32 KB each): gather working
// set fits per-XCD L2. 2 lanes per edge, 16B loads, shfl reduce.
__global__ __launch_bounds__(256) void edge_kernel(
    const int* __restrict__ edge_index,  // [2][n_edges]
    const int* __restrict__ edge_type,   // [n_edges]
    const __half* __restrict__ h1,
    const __half* __restrict__ h2,
    const __half* __restrict__ w1h,      // [1000][16]
    const __half* __restrict__ w2h,
    float* __restrict__ out,
    int n_edges) {
  int tid = (int)blockIdx.x * 256 + (int)threadIdx.x;
  int e = tid >> 1;
  int q = tid & 1;
  if (e >= n_edges) return;

  int src = edge_index[e];
  int dst = edge_index[n_edges + e];
  int t   = edge_type[e];

  float4 araw = *reinterpret_cast<const float4*>(h1  + (size_t)src * L1_DIM + q * 8);
  float4 braw = *reinterpret_cast<const float4*>(h2  + (size_t)dst * L1_DIM + q * 8);
  float4 uraw = *reinterpret_cast<const float4*>(w1h + (size_t)t   * L1_DIM + q * 8);
  float4 vraw = *reinterpret_cast<const float4*>(w2h + (size_t)t   * L1_DIM + q * 8);

  const __half2* A = reinterpret_cast<const __half2*>(&araw);
  const __half2* B = reinterpret_cast<const __half2*>(&braw);
  const __half2* U = reinterpret_cast<const __half2*>(&uraw);
  const __half2* V = reinterpret_cast<const __half2*>(&vraw);

  float s = 0.f;
#pragma unroll
  for (int p = 0; p < 4; ++p) {
    float2 af = __half22float2(A[p]);
    float2 uf = __half22float2(U[p]);
    float2 bf = __half22float2(B[p]);
    float2 vf = __half22float2(V[p]);
    s = fmaf(af.x, uf.x, s);
    s = fmaf(af.y, uf.y, s);
    s = fmaf(bf.x, vf.x, s);
    s = fmaf(bf.y, vf.y, s);
  }

  s += __shfl_xor(s, 1);

  if (q == 0) {
    out[e] = 1.0f / (1.0f + __expf(-s));
  }
}

extern "C" void kernel_launch(void* const* d_in, const int* in_sizes, int n_in,
                              void* d_out, int out_size, void* d_ws, size_t ws_size,
                              hipStream_t stream) {
  const float* z      = (const float*)d_in[0];
  const int* edge_idx = (const int*)d_in[1];
  const int* edge_typ = (const int*)d_in[2];
  const float* w1_l1  = (const float*)d_in[3];
  const float* w1_l2  = (const float*)d_in[4];
  const float* w2_l1  = (const float*)d_in[5];
  const float* w2_l2  = (const float*)d_in[6];
  float* out = (float*)d_out;

  int n_nodes = in_sizes[0] / IN_DIM;
  int n_edges = in_sizes[2];

  __half* h1  = (__half*)d_ws;
  __half* h2  = h1 + (size_t)n_nodes * L1_DIM;
  __half* w1h = h2 + (size_t)n_nodes * L1_DIM;
  __half* w2h = w1h + 1000 * L1_DIM;

  {
    int nblocks_proj = (n_nodes + NPB - 1) / NPB;  // 782
    int grid = nblocks_proj + 8;                   // +8 blocks: w fp16 convert
    proj_kernel<<<grid, PBLOCK, 0, stream>>>(z, w1_l1, w2_l1, w1_l2, w2_l2,
                                             h1, h2, w1h, w2h,
                                             n_nodes, nblocks_proj);
  }
  {
    long long threads = (long long)n_edges * 2;
    int block = 256;
    int grid = (int)((threads + block - 1) / block);
    edge_kernel<<<grid, block, 0, stream>>>(edge_idx, edge_typ, h1, h2,
                                            w1h, w2h, out, n_edges);
  }
}

// Round 5
// 68.416 us; speedup vs baseline: 4.6256x; 4.6256x over previous
//
#include <hip/hip_runtime.h>
#include <hip/hip_fp16.h>
#include <math.h>

#define IN_DIM 256
#define L1_DIM 16

// ---------------- proj kernel ----------------
// Block = 256 threads = 4 waves over a 64-node tile. Whole z-tile staged in
// LDS ONCE (stride 260 words -> ds_write_b128/ds_read_b128 both at the
// conflict-free minimum), ONE barrier, then wave w = (table w<2, j-half w&1)
// runs a straight 2048-FMA loop with lane = node. No double-buffer, no
// runtime-selected register arrays (R4 lesson: rule #20 scratch blowup).
#define NPB 64
#define PBLOCK 256
#define ZSTRIDE 260             // words; 260%32=4 -> b128 ops conflict-free
#define F4PT 16                 // 64 rows * 64 f4/row / 256 threads

__global__ __launch_bounds__(PBLOCK) void proj_kernel(
    const float* __restrict__ z,
    const float* __restrict__ w1,   // [256][16]
    const float* __restrict__ w2,
    __half* __restrict__ h1,        // [n_nodes][16] fp16
    __half* __restrict__ h2,
    int n_nodes) {
  __shared__ float zs[NPB * ZSTRIDE];   // 65.0 KB -> 2 blocks/CU

  const int tid  = threadIdx.x;
  const int lane = tid & 63;
  const int wv   = __builtin_amdgcn_readfirstlane(tid >> 6);  // 0..3
  const int node0 = (int)blockIdx.x * NPB;

  // ---- stage whole tile: 16 coalesced float4 loads per thread ----
  float4 buf[F4PT];
#pragma unroll
  for (int r = 0; r < F4PT; ++r) {
    int slot = r * PBLOCK + tid;     // 0..4095
    int nd = slot >> 6;              // row (64 f4 per row)
    int c4 = slot & 63;
    int ng = node0 + nd;
    if (ng >= n_nodes) ng = n_nodes - 1;   // clamp, stay in bounds
    buf[r] = *reinterpret_cast<const float4*>(
        z + (size_t)ng * IN_DIM + c4 * 4);
  }
#pragma unroll
  for (int r = 0; r < F4PT; ++r) {
    int slot = r * PBLOCK + tid;
    int nd = slot >> 6;
    int c4 = slot & 63;
    *reinterpret_cast<float4*>(&zs[nd * ZSTRIDE + c4 * 4]) = buf[r];
  }
  __syncthreads();

  // ---- compute: wave picks table + j-half; lane = node ----
  const float* wsel = (wv < 2) ? w1 : w2;     // scalar select
  __half*      hsel = (wv < 2) ? h1 : h2;
  const int jbase = (wv & 1) * 8;

  float acc[8];
#pragma unroll
  for (int j = 0; j < 8; ++j) acc[j] = 0.f;

  const float* zrow = &zs[lane * ZSTRIDE];
#pragma unroll 8
  for (int k4 = 0; k4 < IN_DIM / 4; ++k4) {
    float4 zk = *reinterpret_cast<const float4*>(zrow + 4 * k4);  // b128, free
    const float* wr = wsel + (size_t)(k4 * 4) * L1_DIM + jbase;   // uniform
#pragma unroll
    for (int j = 0; j < 8; ++j) {
      acc[j] = fmaf(zk.x, wr[0 * L1_DIM + j], acc[j]);
      acc[j] = fmaf(zk.y, wr[1 * L1_DIM + j], acc[j]);
      acc[j] = fmaf(zk.z, wr[2 * L1_DIM + j], acc[j]);
      acc[j] = fmaf(zk.w, wr[3 * L1_DIM + j], acc[j]);
    }
  }

  int node = node0 + lane;
  if (node < n_nodes) {
    union { __half2 h[4]; float4 f; } o;
    o.h[0] = __floats2half2_rn(fmaxf(acc[0], 0.f), fmaxf(acc[1], 0.f));
    o.h[1] = __floats2half2_rn(fmaxf(acc[2], 0.f), fmaxf(acc[3], 0.f));
    o.h[2] = __floats2half2_rn(fmaxf(acc[4], 0.f), fmaxf(acc[5], 0.f));
    o.h[3] = __floats2half2_rn(fmaxf(acc[6], 0.f), fmaxf(acc[7], 0.f));
    // byte offset node*32 + jbase*2 -> 16B aligned
    *reinterpret_cast<float4*>(hsel + (size_t)node * L1_DIM + jbase) = o.f;
  }
}

// ---------------- w-table fp16 conversion ----------------
__global__ __launch_bounds__(256) void convert_kernel(
    const float* __restrict__ w1_l2,
    const float* __restrict__ w2_l2,
    __half* __restrict__ w1h,
    __half* __restrict__ w2h,
    int total) {
  int i = (int)blockIdx.x * 256 + (int)threadIdx.x;
  if (i < total) {
    w1h[i] = __float2half(w1_l2[i]);
    w2h[i] = __float2half(w2_l2[i]);
  }
}

// ---------------- edge kernel ----------------
// fp16 h tables (3.2 MB) + fp16 w tables (64 KB): gather set is L2-resident.
// 2 lanes per edge, 16B gathers, one shfl_xor reduce.
__global__ __launch_bounds__(256) void edge_kernel(
    const int* __restrict__ edge_index,  // [2][n_edges]
    const int* __restrict__ edge_type,   // [n_edges]
    const __half* __restrict__ h1,
    const __half* __restrict__ h2,
    const __half* __restrict__ w1h,      // [1000][16]
    const __half* __restrict__ w2h,
    float* __restrict__ out,
    int n_edges) {
  int tid = (int)blockIdx.x * 256 + (int)threadIdx.x;
  int e = tid >> 1;
  int q = tid & 1;
  if (e >= n_edges) return;

  int src = edge_index[e];
  int dst = edge_index[n_edges + e];
  int t   = edge_type[e];

  float4 araw = *reinterpret_cast<const float4*>(h1  + (size_t)src * L1_DIM + q * 8);
  float4 braw = *reinterpret_cast<const float4*>(h2  + (size_t)dst * L1_DIM + q * 8);
  float4 uraw = *reinterpret_cast<const float4*>(w1h + (size_t)t   * L1_DIM + q * 8);
  float4 vraw = *reinterpret_cast<const float4*>(w2h + (size_t)t   * L1_DIM + q * 8);

  const __half2* A = reinterpret_cast<const __half2*>(&araw);
  const __half2* B = reinterpret_cast<const __half2*>(&braw);
  const __half2* U = reinterpret_cast<const __half2*>(&uraw);
  const __half2* V = reinterpret_cast<const __half2*>(&vraw);

  float s = 0.f;
#pragma unroll
  for (int p = 0; p < 4; ++p) {
    float2 af = __half22float2(A[p]);
    float2 uf = __half22float2(U[p]);
    float2 bf = __half22float2(B[p]);
    float2 vf = __half22float2(V[p]);
    s = fmaf(af.x, uf.x, s);
    s = fmaf(af.y, uf.y, s);
    s = fmaf(bf.x, vf.x, s);
    s = fmaf(bf.y, vf.y, s);
  }

  s += __shfl_xor(s, 1);

  if (q == 0) {
    out[e] = 1.0f / (1.0f + __expf(-s));
  }
}

extern "C" void kernel_launch(void* const* d_in, const int* in_sizes, int n_in,
                              void* d_out, int out_size, void* d_ws, size_t ws_size,
                              hipStream_t stream) {
  const float* z      = (const float*)d_in[0];
  const int* edge_idx = (const int*)d_in[1];
  const int* edge_typ = (const int*)d_in[2];
  const float* w1_l1  = (const float*)d_in[3];
  const float* w1_l2  = (const float*)d_in[4];
  const float* w2_l1  = (const float*)d_in[5];
  const float* w2_l2  = (const float*)d_in[6];
  float* out = (float*)d_out;

  int n_nodes = in_sizes[0] / IN_DIM;
  int n_edges = in_sizes[2];
  int n_l2    = in_sizes[4];      // 1000*16

  __half* h1  = (__half*)d_ws;
  __half* h2  = h1 + (size_t)n_nodes * L1_DIM;
  __half* w1h = h2 + (size_t)n_nodes * L1_DIM;
  __half* w2h = w1h + (size_t)n_l2;

  {
    int grid = (n_l2 + 255) / 256;
    convert_kernel<<<grid, 256, 0, stream>>>(w1_l2, w2_l2, w1h, w2h, n_l2);
  }
  {
    int grid = (n_nodes + NPB - 1) / NPB;
    proj_kernel<<<grid, PBLOCK, 0, stream>>>(z, w1_l1, w2_l1, h1, h2, n_nodes);
  }
  {
    long long threads = (long long)n_edges * 2;
    int block = 256;
    int grid = (int)((threads + block - 1) / block);
    edge_kernel<<<grid, block, 0, stream>>>(edge_idx, edge_typ, h1, h2,
                                            w1h, w2h, out, n_edges);
  }
}

// Round 6
// 37.641 us; speedup vs baseline: 8.4075x; 1.8176x over previous
//
#include <hip/hip_runtime.h>
#include <hip/hip_fp16.h>
#include <math.h>

#define IN_DIM 256
#define L1_DIM 16

typedef _Float16 f16x8 __attribute__((ext_vector_type(8)));
typedef float f32x4 __attribute__((ext_vector_type(4)));

// ---------------- proj kernel (MFMA f16) ----------------
// GEMM M=n_nodes, N=32 ([w1|w2]), K=256 via mfma_f32_16x16x32_f16.
// Block = 256 = 4 waves, M=64 nodes/block, wave w owns rows 16w..16w+15.
// No LDS, no barrier: lane (q=l>>4, r=l&15) loads its A-fragment directly
// from global (row node0+16w+r, k = 32s+8q..+7 -> 32 contiguous bytes);
// a wave instruction covers 16 rows x 128 B contiguous = full lines.
// B fragments (both weight tables, fp16) preloaded once into 64 VGPRs.
// Trailing 8 blocks convert w*_l2 to fp16 for the edge kernel.
__global__ __launch_bounds__(256) void proj_kernel(
    const float* __restrict__ z,
    const float* __restrict__ w1,     // [256][16]
    const float* __restrict__ w2,
    const float* __restrict__ w1_l2,  // [1000][16]
    const float* __restrict__ w2_l2,
    __half* __restrict__ h1,          // [n_nodes][16] fp16
    __half* __restrict__ h2,
    __half* __restrict__ w1h,
    __half* __restrict__ w2h,
    int n_nodes, int nblocks_proj) {
  // trailing blocks: convert level-2 weight tables to fp16
  if ((int)blockIdx.x >= nblocks_proj) {
    int t0 = ((int)blockIdx.x - nblocks_proj) * 256 + (int)threadIdx.x;
    const int total = 1000 * L1_DIM;  // 16000
    for (int i = t0; i < total; i += 8 * 256) {
      w1h[i] = __float2half(w1_l2[i]);
      w2h[i] = __float2half(w2_l2[i]);
    }
    return;
  }

  const int tid  = (int)threadIdx.x;
  const int lane = tid & 63;
  const int wv   = tid >> 6;      // 0..3
  const int r    = lane & 15;     // A row-in-tile / B col / D col
  const int q    = lane >> 4;     // k-subgroup 0..3
  const int node0 = (int)blockIdx.x * 64;

  // ---- B fragments: k = 32s + 8q + j, col = r ----
  f16x8 bf1[8], bf2[8];
#pragma unroll
  for (int s = 0; s < 8; ++s) {
#pragma unroll
    for (int j = 0; j < 8; ++j) {
      int k = 32 * s + 8 * q + j;
      bf1[s][j] = (_Float16)w1[k * L1_DIM + r];
      bf2[s][j] = (_Float16)w2[k * L1_DIM + r];
    }
  }

  // ---- A row pointer (clamped for tail block) ----
  int arow = node0 + wv * 16 + r;
  int ar = arow < n_nodes ? arow : (n_nodes - 1);
  const float* zrow = z + (size_t)ar * IN_DIM + 8 * q;

  f32x4 acc1 = {0.f, 0.f, 0.f, 0.f};
  f32x4 acc2 = {0.f, 0.f, 0.f, 0.f};

#pragma unroll
  for (int s = 0; s < 8; ++s) {
    float4 lo = *reinterpret_cast<const float4*>(zrow + 32 * s);
    float4 hi = *reinterpret_cast<const float4*>(zrow + 32 * s + 4);
    f16x8 af;
    af[0] = (_Float16)lo.x; af[1] = (_Float16)lo.y;
    af[2] = (_Float16)lo.z; af[3] = (_Float16)lo.w;
    af[4] = (_Float16)hi.x; af[5] = (_Float16)hi.y;
    af[6] = (_Float16)hi.z; af[7] = (_Float16)hi.w;
    acc1 = __builtin_amdgcn_mfma_f32_16x16x32_f16(af, bf1[s], acc1, 0, 0, 0);
    acc2 = __builtin_amdgcn_mfma_f32_16x16x32_f16(af, bf2[s], acc2, 0, 0, 0);
  }

  // ---- D layout: col = r, row = 4q + i -> node = node0 + 16wv + 4q + i ----
#pragma unroll
  for (int i = 0; i < 4; ++i) {
    int node = node0 + wv * 16 + 4 * q + i;
    if (node < n_nodes) {
      h1[(size_t)node * L1_DIM + r] = __float2half(fmaxf(acc1[i], 0.f));
      h2[(size_t)node * L1_DIM + r] = __float2half(fmaxf(acc2[i], 0.f));
    }
  }
}

// ---------------- edge kernel ----------------
// fp16 h tables (3.2 MB) + fp16 w tables (64 KB): gather set is L2-resident.
// 2 lanes per edge, 16B gathers, one shfl_xor reduce.
__global__ __launch_bounds__(256) void edge_kernel(
    const int* __restrict__ edge_index,  // [2][n_edges]
    const int* __restrict__ edge_type,   // [n_edges]
    const __half* __restrict__ h1,
    const __half* __restrict__ h2,
    const __half* __restrict__ w1h,      // [1000][16]
    const __half* __restrict__ w2h,
    float* __restrict__ out,
    int n_edges) {
  int tid = (int)blockIdx.x * 256 + (int)threadIdx.x;
  int e = tid >> 1;
  int q = tid & 1;
  if (e >= n_edges) return;

  int src = edge_index[e];
  int dst = edge_index[n_edges + e];
  int t   = edge_type[e];

  float4 araw = *reinterpret_cast<const float4*>(h1  + (size_t)src * L1_DIM + q * 8);
  float4 braw = *reinterpret_cast<const float4*>(h2  + (size_t)dst * L1_DIM + q * 8);
  float4 uraw = *reinterpret_cast<const float4*>(w1h + (size_t)t   * L1_DIM + q * 8);
  float4 vraw = *reinterpret_cast<const float4*>(w2h + (size_t)t   * L1_DIM + q * 8);

  const __half2* A = reinterpret_cast<const __half2*>(&araw);
  const __half2* B = reinterpret_cast<const __half2*>(&braw);
  const __half2* U = reinterpret_cast<const __half2*>(&uraw);
  const __half2* V = reinterpret_cast<const __half2*>(&vraw);

  float s = 0.f;
#pragma unroll
  for (int p = 0; p < 4; ++p) {
    float2 af = __half22float2(A[p]);
    float2 uf = __half22float2(U[p]);
    float2 bf = __half22float2(B[p]);
    float2 vf = __half22float2(V[p]);
    s = fmaf(af.x, uf.x, s);
    s = fmaf(af.y, uf.y, s);
    s = fmaf(bf.x, vf.x, s);
    s = fmaf(bf.y, vf.y, s);
  }

  s += __shfl_xor(s, 1);

  if (q == 0) {
    out[e] = 1.0f / (1.0f + __expf(-s));
  }
}

extern "C" void kernel_launch(void* const* d_in, const int* in_sizes, int n_in,
                              void* d_out, int out_size, void* d_ws, size_t ws_size,
                              hipStream_t stream) {
  const float* z      = (const float*)d_in[0];
  const int* edge_idx = (const int*)d_in[1];
  const int* edge_typ = (const int*)d_in[2];
  const float* w1_l1  = (const float*)d_in[3];
  const float* w1_l2  = (const float*)d_in[4];
  const float* w2_l1  = (const float*)d_in[5];
  const float* w2_l2  = (const float*)d_in[6];
  float* out = (float*)d_out;

  int n_nodes = in_sizes[0] / IN_DIM;
  int n_edges = in_sizes[2];
  int n_l2    = in_sizes[4];      // 1000*16

  __half* h1  = (__half*)d_ws;
  __half* h2  = h1 + (size_t)n_nodes * L1_DIM;
  __half* w1h = h2 + (size_t)n_nodes * L1_DIM;
  __half* w2h = w1h + (size_t)n_l2;

  {
    int nblocks_proj = (n_nodes + 63) / 64;   // 782
    int grid = nblocks_proj + 8;              // +8 blocks: w fp16 convert
    proj_kernel<<<grid, 256, 0, stream>>>(z, w1_l1, w2_l1, w1_l2, w2_l2,
                                          h1, h2, w1h, w2h,
                                          n_nodes, nblocks_proj);
  }
  {
    long long threads = (long long)n_edges * 2;
    int block = 256;
    int grid = (int)((threads + block - 1) / block);
    edge_kernel<<<grid, block, 0, stream>>>(edge_idx, edge_typ, h1, h2,
                                            w1h, w2h, out, n_edges);
  }
}